// Round 11
// baseline (2053.635 us; speedup 1.0000x reference)
//
#include <hip/hip_runtime.h>

#define WF 64

__device__ inline float wredsum(float v) {
#pragma unroll
  for (int m = 32; m; m >>= 1) v += __shfl_xor(v, m, WF);
  return v;
}
__device__ inline float4 wredsum4(float4 v) {
#pragma unroll
  for (int m = 32; m; m >>= 1) {
    v.x += __shfl_xor(v.x, m, WF);
    v.y += __shfl_xor(v.y, m, WF);
    v.z += __shfl_xor(v.z, m, WF);
    v.w += __shfl_xor(v.w, m, WF);
  }
  return v;
}
__device__ inline float wredmin(float v) {
#pragma unroll
  for (int m = 32; m; m >>= 1) v = fminf(v, __shfl_xor(v, m, WF));
  return v;
}
__device__ inline float wredmax(float v) {
#pragma unroll
  for (int m = 32; m; m >>= 1) v = fmaxf(v, __shfl_xor(v, m, WF));
  return v;
}

__device__ inline float fastrcp(float x) {
  float r;
  asm("v_rcp_f32 %0, %1" : "=v"(r) : "v"(x));
  return r;
}

__device__ inline void atomAddF(float* p, float v) { unsafeAtomicAdd(p, v); }

// ---------------- shared-memory union (conv path vs rank path) ----------------
struct ConvS {
  float Wl[4096];
  float rowbuf[4][64];
  float red[4][5];
  float colred[4][64];
  float mvs[4];
  int mis[4];
};
struct RankS {
  float A[64][65];
  float vbuf[64], wbuf[64], esh[64];
  float wpart[4][64];
  float2 de[64];
  float u[64], m0[64];
  float shn;
};
union SmemU {
  ConvS c;
  RankS r;
};

// ---------------- init ----------------
__global__ __launch_bounds__(256) void k_init(int* degs, int* degd, float* G,
                                              float* colsum, float* scal, int n) {
  int i = blockIdx.x * 256 + threadIdx.x;
  if (i < n) { degs[i] = 1; degd[i] = 1; }
  if (i < 3 * 4096) G[i] = 0.f;
  if (i < 3 * 64) colsum[i] = 0.f;
  if (i < 64) scal[i] = 0.f;
}

// ---------------- degree histograms ----------------
__global__ __launch_bounds__(256) void k_deg(const int* src, const int* dst,
                                             int* degs, int* degd, int e) {
  int i = blockIdx.x * 256 + threadIdx.x;
  int stride = gridDim.x * 256;
  for (; i < e; i += stride) {
    atomicAdd(&degs[src[i]], 1);
    atomicAdd(&degd[dst[i]], 1);
  }
}

// ---------------- per-node constants ----------------
__global__ __launch_bounds__(256) void k_nodescal(const int* degs, const int* degd,
                                                  float4* cn4, float* degsum, int n) {
  int i = blockIdx.x * 256 + threadIdx.x;
  if (i < n) {
    float fs = (float)degs[i], fd = (float)degd[i];
    float rs_ = rsqrtf(fs);
    float4 v;
    v.x = rsqrtf(fd);        // dis (GCN norm)
    v.y = 1.f / fs;          // 1/deg_src
    v.z = rs_;               // deg_src^-0.5
    v.w = rs_ * rs_ * rs_;   // deg_src^-1.5
    cn4[i] = v;
    degsum[i] = fs + fd;
  }
}

// ---------------- scan ----------------
__global__ __launch_bounds__(256) void k_scan1(const int* degd, int* start, int* bsum, int n) {
  __shared__ int sb[256];
  int t = threadIdx.x, i = blockIdx.x * 256 + t;
  int v = (i < n) ? degd[i] : 0;
  sb[t] = v;
  __syncthreads();
  for (int off = 1; off < 256; off <<= 1) {
    int add = (t >= off) ? sb[t - off] : 0;
    __syncthreads();
    sb[t] += add;
    __syncthreads();
  }
  if (i < n) start[i] = sb[t] - v;
  if (t == 255) bsum[blockIdx.x] = sb[255];
}

__global__ __launch_bounds__(512) void k_scan2(int* bsum, int nb) {
  __shared__ int sb[512];
  int t = threadIdx.x;
  int v = (t < nb) ? bsum[t] : 0;
  sb[t] = v;
  __syncthreads();
  for (int off = 1; off < 512; off <<= 1) {
    int add = (t >= off) ? sb[t - off] : 0;
    __syncthreads();
    sb[t] += add;
    __syncthreads();
  }
  if (t < nb) bsum[t] = sb[t] - v;
}

__global__ __launch_bounds__(256) void k_scan3(int* start, const int* bsum, int* cursor,
                                               int n, int total) {
  int i = blockIdx.x * 256 + threadIdx.x;
  if (i < n) {
    int v = start[i] + bsum[i >> 8];
    start[i] = v;
    cursor[i] = v;
  }
  if (i == 0) start[n] = total;
}

// ---------------- counting-sort edges by dst ----------------
__global__ __launch_bounds__(256) void k_scatter(const int* src, const int* dst, int* cursor,
                                                 int* csr, int e, int n) {
  int i = blockIdx.x * 256 + threadIdx.x;
  int tot = e + n;
  if (i >= tot) return;
  int s, d;
  if (i < e) { s = src[i]; d = dst[i]; } else { s = i - e; d = i - e; }
  int pos = atomicAdd(&cursor[d], 1);
  csr[pos] = s;
}

// ---------------- encoder: X = x @ enc_w + b ; nsq, P0 ----------------
__global__ __launch_bounds__(256) void k_enc(const float* __restrict__ x,
                                             const float* __restrict__ W,
                                             const float* __restrict__ b,
                                             const float4* __restrict__ cn4,
                                             float* __restrict__ X,
                                             float* __restrict__ nsq,
                                             float4* __restrict__ P, int n) {
  __shared__ float Wl[128 * 64];
  for (int idx = threadIdx.x; idx < 128 * 64; idx += 256) Wl[idx] = W[idx];
  __syncthreads();
  int w = threadIdx.x >> 6, c = threadIdx.x & 63;
  float bc = b[c];
  for (int node = blockIdx.x * 4 + w; node < n; node += gridDim.x * 4) {
    const float4* xr4 = (const float4*)(x + (size_t)node * 128);
    float acc = bc;
#pragma unroll
    for (int k4 = 0; k4 < 32; k4++) {
      float4 xv = xr4[k4];
      acc += xv.x * Wl[(k4 * 4 + 0) * 64 + c];
      acc += xv.y * Wl[(k4 * 4 + 1) * 64 + c];
      acc += xv.z * Wl[(k4 * 4 + 2) * 64 + c];
      acc += xv.w * Wl[(k4 * 4 + 3) * 64 + c];
    }
    X[(size_t)node * 64 + c] = acc;
    float r = wredsum(acc * acc);
    if (c == 0) {
      nsq[node] = r;
      float4 c4 = cn4[node];
      P[node] = make_float4(c4.x, c4.y, c4.z, r * c4.w);
    }
  }
}

// ---------------- 4-deep unrolled gather core (per 16-lane group) ----------------
// Accumulates agg0 = Sigma h_s, agg1 = Sigma h_s/deg_s, aggC = Sigma dis_s*h_s
// (AGGC=0 skips aggC), su = Sigma nsq[s]*degs^-1.5, sv = Sigma degs^-0.5.
template <int AGGC>
__device__ inline void gather4(const float* __restrict__ H, const float4* __restrict__ P,
                               const int* __restrict__ csr, int k0, int k1, int g, int l16,
                               float4& agg0, float4& agg1, float4& aggC,
                               float& su, float& sv) {
  int kk = k0 + g;
  int last = k1 - 1;
  int s0 = csr[min(kk, last)];
  int s1 = csr[min(kk + 4, last)];
  int s2 = csr[min(kk + 8, last)];
  int s3 = csr[min(kk + 12, last)];
  while (kk < k1) {
    int kn = kk + 16;
    float4 h0 = *(const float4*)(H + (size_t)s0 * 64 + 4 * l16);
    float4 h1 = *(const float4*)(H + (size_t)s1 * 64 + 4 * l16);
    float4 h2 = *(const float4*)(H + (size_t)s2 * 64 + 4 * l16);
    float4 h3 = *(const float4*)(H + (size_t)s3 * 64 + 4 * l16);
    float4 Q0 = P[s0], Q1 = P[s1], Q2 = P[s2], Q3 = P[s3];
    s0 = csr[min(kn, last)];
    s1 = csr[min(kn + 4, last)];
    s2 = csr[min(kn + 8, last)];
    s3 = csr[min(kn + 12, last)];
    float m1 = (kk + 4 < k1) ? 1.f : 0.f;
    float m2 = (kk + 8 < k1) ? 1.f : 0.f;
    float m3 = (kk + 12 < k1) ? 1.f : 0.f;
    // edge 0 (always valid inside loop)
    agg0.x += h0.x; agg0.y += h0.y; agg0.z += h0.z; agg0.w += h0.w;
    agg1.x = fmaf(h0.x, Q0.y, agg1.x); agg1.y = fmaf(h0.y, Q0.y, agg1.y);
    agg1.z = fmaf(h0.z, Q0.y, agg1.z); agg1.w = fmaf(h0.w, Q0.y, agg1.w);
    if (AGGC) {
      aggC.x = fmaf(h0.x, Q0.x, aggC.x); aggC.y = fmaf(h0.y, Q0.x, aggC.y);
      aggC.z = fmaf(h0.z, Q0.x, aggC.z); aggC.w = fmaf(h0.w, Q0.x, aggC.w);
    }
    su += Q0.w; sv += Q0.z;
    // edge 1
    {
      float y = Q1.y * m1;
      agg0.x = fmaf(h1.x, m1, agg0.x); agg0.y = fmaf(h1.y, m1, agg0.y);
      agg0.z = fmaf(h1.z, m1, agg0.z); agg0.w = fmaf(h1.w, m1, agg0.w);
      agg1.x = fmaf(h1.x, y, agg1.x); agg1.y = fmaf(h1.y, y, agg1.y);
      agg1.z = fmaf(h1.z, y, agg1.z); agg1.w = fmaf(h1.w, y, agg1.w);
      if (AGGC) {
        float xq = Q1.x * m1;
        aggC.x = fmaf(h1.x, xq, aggC.x); aggC.y = fmaf(h1.y, xq, aggC.y);
        aggC.z = fmaf(h1.z, xq, aggC.z); aggC.w = fmaf(h1.w, xq, aggC.w);
      }
      su = fmaf(Q1.w, m1, su); sv = fmaf(Q1.z, m1, sv);
    }
    // edge 2
    {
      float y = Q2.y * m2;
      agg0.x = fmaf(h2.x, m2, agg0.x); agg0.y = fmaf(h2.y, m2, agg0.y);
      agg0.z = fmaf(h2.z, m2, agg0.z); agg0.w = fmaf(h2.w, m2, agg0.w);
      agg1.x = fmaf(h2.x, y, agg1.x); agg1.y = fmaf(h2.y, y, agg1.y);
      agg1.z = fmaf(h2.z, y, agg1.z); agg1.w = fmaf(h2.w, y, agg1.w);
      if (AGGC) {
        float xq = Q2.x * m2;
        aggC.x = fmaf(h2.x, xq, aggC.x); aggC.y = fmaf(h2.y, xq, aggC.y);
        aggC.z = fmaf(h2.z, xq, aggC.z); aggC.w = fmaf(h2.w, xq, aggC.w);
      }
      su = fmaf(Q2.w, m2, su); sv = fmaf(Q2.z, m2, sv);
    }
    // edge 3
    {
      float y = Q3.y * m3;
      agg0.x = fmaf(h3.x, m3, agg0.x); agg0.y = fmaf(h3.y, m3, agg0.y);
      agg0.z = fmaf(h3.z, m3, agg0.z); agg0.w = fmaf(h3.w, m3, agg0.w);
      agg1.x = fmaf(h3.x, y, agg1.x); agg1.y = fmaf(h3.y, y, agg1.y);
      agg1.z = fmaf(h3.z, y, agg1.z); agg1.w = fmaf(h3.w, y, agg1.w);
      if (AGGC) {
        float xq = Q3.x * m3;
        aggC.x = fmaf(h3.x, xq, aggC.x); aggC.y = fmaf(h3.y, xq, aggC.y);
        aggC.z = fmaf(h3.z, xq, aggC.z); aggC.w = fmaf(h3.w, xq, aggC.w);
      }
      su = fmaf(Q3.w, m3, su); sv = fmaf(Q3.z, m3, sv);
    }
    kk = kn;
  }
}

// ---------------- Householder tridiag (trailing-only) + Sturm bisection -------------
__device__ float tridiag_sumsqrt(RankS& S, int t) {
  bool w0 = (t < 64);
  int lane = t & 63, w4 = t >> 6;
  for (int k = 0; k < 62; k++) {
    float beta = 0.f;
    if (w0) {
      float acol = S.A[t][k];
      float xs = (t >= k + 2) ? acol : 0.f;
      float sigma = wredsum(xs * xs);
      float x1 = __shfl(acol, k + 1, WF);
      float alpha = -copysignf(sqrtf(fmaf(x1, x1, sigma)), x1);
      float v1 = x1 - alpha;
      float vv = fmaf(v1, v1, sigma);
      beta = (vv > 1e-37f) ? 2.f / vv : 0.f;
      S.vbuf[t] = (t == k + 1) ? v1 : xs;   // zero for t<=k
      if (t == 0) S.esh[k] = alpha;
    }
    __syncthreads();
    {
      // trailing-only matvec: skip j<=k (vbuf[j]==0), wave-uniform guards
      float s0 = 0.f, s1 = 0.f, s2 = 0.f, s3 = 0.f;
#pragma unroll
      for (int i2 = 0; i2 < 4; i2++) {
        int j = w4 + 16 * i2;
        if (j > k)      s0 = fmaf(S.A[lane][j], S.vbuf[j], s0);
        if (j + 4 > k)  s1 = fmaf(S.A[lane][j + 4], S.vbuf[j + 4], s1);
        if (j + 8 > k)  s2 = fmaf(S.A[lane][j + 8], S.vbuf[j + 8], s2);
        if (j + 12 > k) s3 = fmaf(S.A[lane][j + 12], S.vbuf[j + 12], s3);
      }
      S.wpart[w4][lane] = (s0 + s1) + (s2 + s3);
    }
    __syncthreads();
    if (w0) {
      float p = beta * (S.wpart[0][t] + S.wpart[1][t] + S.wpart[2][t] + S.wpart[3][t]);
      float dot = wredsum(S.vbuf[t] * p);
      float K = 0.5f * beta * dot;
      S.wbuf[t] = fmaf(-K, S.vbuf[t], p);
    }
    __syncthreads();
    {
      // trailing-only rank-2 update: only rows i>k matter
      float vj = S.vbuf[lane], wj = S.wbuf[lane];
#pragma unroll
      for (int i2 = 0; i2 < 16; i2++) {
        int i = w4 + 4 * i2;
        if (i > k) S.A[i][lane] -= S.vbuf[i] * wj + S.wbuf[i] * vj;
      }
    }
    __syncthreads();
  }
  if (t == 0) { S.esh[62] = S.A[63][62]; S.esh[63] = 0.f; }
  __syncthreads();
  float gmin = 0.f, gmax = 0.f;
  if (w0) {
    float dt = S.A[t][t];
    float ep = (t >= 1) ? S.esh[t - 1] : 0.f;
    float en = (t <= 62) ? S.esh[t] : 0.f;
    S.de[t] = make_float2(dt, ep * ep);
    float rad = fabsf(ep) + fabsf(en);
    gmin = wredmin(dt - rad);
    gmax = wredmax(dt + rad);
  }
  __syncthreads();
  float lam = 0.f;
  if (w0) {
    float range = gmax - gmin;
    float lo = gmin - 1e-3f * range - 1e-30f;
    float hi = gmax + 1e-3f * range + 1e-30f;
    for (int it = 0; it < 30; it++) {
      float mid = 0.5f * (lo + hi);
      float q = S.de[0].x - mid;
      int cnt = (q < 0.f) ? 1 : 0;
      for (int i = 1; i < 64; i++) {
        float2 dc = S.de[i];
        float qq = (dc.x - mid) - dc.y * fastrcp(q);
        q = (fabsf(qq) < 1e-30f) ? -1e-30f : qq;
        cnt += (q < 0.f) ? 1 : 0;
      }
      if (cnt > t) hi = mid; else lo = mid;
    }
    lam = 0.5f * (lo + hi);
  }
  float svv = w0 ? sqrtf(fmaxf(lam, 0.f)) : 0.f;
  return wredsum(svv);
}

// ---------------- one layer's full rank pipeline (2 solves) ----------------
__device__ void rank_block(RankS& S, const float* __restrict__ Gl,
                           const float* __restrict__ rowslot_l,
                           const int* __restrict__ jstar_l,
                           float* __restrict__ rankOut_l, int t) {
  for (int idx = t; idx < 4096; idx += 256) S.A[idx >> 6][idx & 63] = Gl[idx];
  __syncthreads();
  float nuc1 = tridiag_sumsqrt(S, t);
  if (t == 0) S.shn = nuc1;
  __syncthreads();
  float s = 1.f / S.shn;
  int js = jstar_l[0];
  if (t < 64) {
    float rv = rowslot_l[t];
    float rn2 = wredsum(rv * rv);
    float sign = (rowslot_l[js] < 0.f) ? -1.f : 1.f;
    S.m0[t] = sign * rv * rsqrtf(rn2);
    S.u[t] = s * Gl[t * 64 + js] * rsqrtf(Gl[js * 64 + js]);
  }
  __syncthreads();
  float s2 = s * s;
  for (int idx = t; idx < 4096; idx += 256) {
    int i = idx >> 6, j = idx & 63;
    S.A[i][j] = s2 * Gl[idx] - S.u[i] * S.m0[j] - S.m0[i] * S.u[j] + S.m0[i] * S.m0[j];
  }
  __syncthreads();
  float nuc2 = tridiag_sumsqrt(S, t);
  if (t == 0) rankOut_l[0] = nuc2;
}

// ---------------- fused: energy(h_l) + conv -> h_{l+1} + stats(h_{l+1}) ----------------
// Blocks [0,nbC): conv+energy ; block nbC (if launched): rank rider for an
// earlier layer (fully hidden under the gather pass).
__global__ __launch_bounds__(256) void k_convpass(
    const float* __restrict__ H, const float4* __restrict__ P,
    const float* __restrict__ nsq, const float* __restrict__ degsum,
    const float4* __restrict__ cn4, const int* __restrict__ start,
    const int* __restrict__ csr, const float* __restrict__ W,
    const float* __restrict__ bias, float* __restrict__ T,
    float4* __restrict__ Pn, float* __restrict__ nsqN,
    float* __restrict__ scal5, float* __restrict__ G, float* __restrict__ colsum,
    float* __restrict__ bmv, int* __restrict__ bmi, int n, int nbC,
    const float* __restrict__ Gr, const float* __restrict__ rowslotR,
    const int* __restrict__ jstarR, float* __restrict__ rankOutR) {
  __shared__ SmemU sm;
  int t = threadIdx.x, w = t >> 6, lane = t & 63, g = lane >> 4, l16 = lane & 15;
  if ((int)blockIdx.x >= nbC) {
    rank_block(sm.r, Gr, rowslotR, jstarR, rankOutR, t);
    return;
  }
  for (int i = t; i < 4096; i += 256) sm.c.Wl[i] = W[i];
  __syncthreads();
  float a0 = 0.f, a1 = 0.f, a2 = 0.f, a3 = 0.f, a4 = 0.f;
  float Greg[16];
#pragma unroll
  for (int k = 0; k < 16; k++) Greg[k] = 0.f;
  float cacc = 0.f, best = -1.f;
  int bi = 0;
  float bc = bias[lane];
  int wid = blockIdx.x * 4 + w, nw = nbC * 4;
  int iters = (n + nw - 1) / nw;
  for (int it = 0; it < iters; it++) {
    int d = wid + it * nw;
    bool valid = d < n;
    float tv = 0.f;
    if (valid) {
      int k0 = start[d], k1 = start[d + 1];
      float4 hd = *(const float4*)(H + (size_t)d * 64 + 4 * l16);
      float4 pd = P[d];
      float nqd = nsq[d];
      float dsum = degsum[d];
      float4 agg0 = {0.f, 0.f, 0.f, 0.f};
      float4 agg1 = {0.f, 0.f, 0.f, 0.f};
      float4 aggC = {0.f, 0.f, 0.f, 0.f};
      float su = 0.f, sv = 0.f;
      gather4<1>(H, P, csr, k0, k1, g, l16, agg0, agg1, aggC, su, sv);
      float td0 = agg0.x * hd.x + agg0.y * hd.y + agg0.z * hd.z + agg0.w * hd.w;
      float td1 = agg1.x * hd.x + agg1.y * hd.y + agg1.z * hd.z + agg1.w * hd.w;
      float4 r4 = wredsum4(make_float4(td0, td1, su, sv));
      float dot1 = r4.x, dot2 = r4.y;
      su = r4.z * 0.0625f;
      sv = r4.w * 0.0625f;
      a0 += dsum * nqd;
      a1 += dot1;
      a2 += pd.z * su + pd.w * sv;
      a3 += pd.y * dot2;
      a4 += nqd;
      // conv finish: reduce aggC across the 4 groups
      aggC.x += __shfl_xor(aggC.x, 16); aggC.y += __shfl_xor(aggC.y, 16);
      aggC.z += __shfl_xor(aggC.z, 16); aggC.w += __shfl_xor(aggC.w, 16);
      aggC.x += __shfl_xor(aggC.x, 32); aggC.y += __shfl_xor(aggC.y, 32);
      aggC.z += __shfl_xor(aggC.z, 32); aggC.w += __shfl_xor(aggC.w, 32);
      float mv = 0.f;
#pragma unroll
      for (int kq = 0; kq < 16; kq++) {
        float ax = __shfl(aggC.x, kq, 16);
        float ay = __shfl(aggC.y, kq, 16);
        float az = __shfl(aggC.z, kq, 16);
        float aw = __shfl(aggC.w, kq, 16);
        mv += ax * sm.c.Wl[(4 * kq + 0) * 64 + lane];
        mv += ay * sm.c.Wl[(4 * kq + 1) * 64 + lane];
        mv += az * sm.c.Wl[(4 * kq + 2) * 64 + lane];
        mv += aw * sm.c.Wl[(4 * kq + 3) * 64 + lane];
      }
      tv = fmaxf(fmaf(pd.x, mv, bc), 0.f);
      T[(size_t)d * 64 + lane] = tv;
      float r = wredsum(tv * tv);
      float atv = fabsf(tv);
      cacc += atv;
      float rsum = wredsum(atv);
      if (rsum > best) { best = rsum; bi = d; }
      if (lane == 0) {
        nsqN[d] = r;
        float4 c4 = cn4[d];
        Pn[d] = make_float4(c4.x, c4.y, c4.z, r * c4.w);
      }
    }
    // cooperative Gram of the new h (all 4 waves lockstep, every node once)
    sm.c.rowbuf[w][lane] = tv;
    __syncthreads();
#pragma unroll
    for (int rr = 0; rr < 4; rr++) {
      float hj = sm.c.rowbuf[rr][lane];
#pragma unroll
      for (int k = 0; k < 16; k++) Greg[k] = fmaf(sm.c.rowbuf[rr][w + 4 * k], hj, Greg[k]);
    }
    __syncthreads();
  }
#pragma unroll
  for (int k = 0; k < 16; k++) atomAddF(&G[(w + 4 * k) * 64 + lane], Greg[k]);
  sm.c.colred[w][lane] = cacc;
  if (lane == 0) {
    sm.c.red[w][0] = a0; sm.c.red[w][1] = a1; sm.c.red[w][2] = a2;
    sm.c.red[w][3] = a3; sm.c.red[w][4] = a4;
    sm.c.mvs[w] = best; sm.c.mis[w] = bi;
  }
  __syncthreads();
  if (t < 64) {
    float cs = sm.c.colred[0][t] + sm.c.colred[1][t] + sm.c.colred[2][t] + sm.c.colred[3][t];
    atomAddF(&colsum[t], cs);
  }
  if (t == 0) {
#pragma unroll
    for (int j = 0; j < 5; j++)
      atomAddF(&scal5[j], sm.c.red[0][j] + sm.c.red[1][j] + sm.c.red[2][j] + sm.c.red[3][j]);
    float bv = sm.c.mvs[0]; int bix = sm.c.mis[0];
    for (int q = 1; q < 4; q++)
      if (sm.c.mvs[q] > bv || (sm.c.mvs[q] == bv && sm.c.mis[q] < bix)) {
        bv = sm.c.mvs[q]; bix = sm.c.mis[q];
      }
    bmv[blockIdx.x] = bv;
    bmi[blockIdx.x] = bix;
  }
}

// ---------------- finalize argmaxes (one wave) ----------------
__global__ __launch_bounds__(64) void k_finalize(const float* T, const float* bmv,
                                                 const int* bmi, int nblocks,
                                                 const float* colsum, float* rowslot,
                                                 int* jstar, int n) {
  int t = threadIdx.x;
  float bv = -1.f;
  int bix = 0x7fffffff;
  for (int b = t; b < nblocks; b += 64) {
    float v = bmv[b]; int ix = bmi[b];
    if (v > bv || (v == bv && ix < bix)) { bv = v; bix = ix; }
  }
#pragma unroll
  for (int m = 32; m; m >>= 1) {
    float ov = __shfl_xor(bv, m); int oi = __shfl_xor(bix, m);
    if (ov > bv || (ov == bv && oi < bix)) { bv = ov; bix = oi; }
  }
  float cv = colsum[t];
  int cj = t;
#pragma unroll
  for (int m = 32; m; m >>= 1) {
    float ov = __shfl_xor(cv, m); int oj = __shfl_xor(cj, m);
    if (ov > cv || (ov == cv && oj < cj)) { cv = ov; cj = oj; }
  }
  if (t == 0) jstar[0] = cj;
  rowslot[t] = T[(size_t)bix * 64 + t];
}

// ---------------- final: 1 rank block (layer 3) + energy(h3) blocks ----------------
__global__ __launch_bounds__(256) void k_final(
    const float* __restrict__ H, const float4* __restrict__ P,
    const float* __restrict__ nsq, const float* __restrict__ degsum,
    const int* __restrict__ start, const int* __restrict__ csr,
    float* __restrict__ scal5, const float* __restrict__ Gr,
    const float* __restrict__ rowslotR, const int* __restrict__ jstarR,
    float* __restrict__ rankOutR, int n, int nbE) {
  __shared__ SmemU sm;
  int t = threadIdx.x, w = t >> 6, lane = t & 63, g = lane >> 4, l16 = lane & 15;
  if (blockIdx.x == 0) {
    rank_block(sm.r, Gr, rowslotR, jstarR, rankOutR, t);
    return;
  }
  float a0 = 0.f, a1 = 0.f, a2 = 0.f, a3 = 0.f, a4 = 0.f;
  int wid = (blockIdx.x - 1) * 4 + w, nw = nbE * 4;
  for (int d = wid; d < n; d += nw) {
    int k0 = start[d], k1 = start[d + 1];
    float4 hd = *(const float4*)(H + (size_t)d * 64 + 4 * l16);
    float4 pd = P[d];
    float nqd = nsq[d];
    float dsum = degsum[d];
    float4 agg0 = {0.f, 0.f, 0.f, 0.f};
    float4 agg1 = {0.f, 0.f, 0.f, 0.f};
    float4 aggC = {0.f, 0.f, 0.f, 0.f};
    float su = 0.f, sv = 0.f;
    gather4<0>(H, P, csr, k0, k1, g, l16, agg0, agg1, aggC, su, sv);
    float td0 = agg0.x * hd.x + agg0.y * hd.y + agg0.z * hd.z + agg0.w * hd.w;
    float td1 = agg1.x * hd.x + agg1.y * hd.y + agg1.z * hd.z + agg1.w * hd.w;
    float4 r4 = wredsum4(make_float4(td0, td1, su, sv));
    a0 += dsum * nqd;
    a1 += r4.x;
    a2 += pd.z * (r4.z * 0.0625f) + pd.w * (r4.w * 0.0625f);
    a3 += pd.y * r4.y;
    a4 += nqd;
  }
  if (lane == 0) {
    sm.c.red[w][0] = a0; sm.c.red[w][1] = a1; sm.c.red[w][2] = a2;
    sm.c.red[w][3] = a3; sm.c.red[w][4] = a4;
  }
  __syncthreads();
  if (t == 0) {
#pragma unroll
    for (int j = 0; j < 5; j++)
      atomAddF(&scal5[j], sm.c.red[0][j] + sm.c.red[1][j] + sm.c.red[2][j] + sm.c.red[3][j]);
  }
}

// ---------------- epilogue ----------------
// scal: [5*st..5*st+4] = {rw_node, rw_dot, sym_AB, sym_C, ss}; [20..22] ranks
__global__ __launch_bounds__(64) void k_epi(const float* scal, float* outsc) {
  if (threadIdx.x == 0) {
    for (int st = 0; st < 4; st++) {
      const float* a = scal + 5 * st;
      float inv = 1.f / a[4];
      float rw = 0.5f * (a[0] - 2.f * a[1]) * inv;
      float sym = 0.5f * (a[2] - 2.f * a[3]) * inv;
      if (st == 0) outsc[0] = sym;
      else { outsc[st] = rw; outsc[3 + st] = sym; }
    }
    for (int l = 0; l < 3; l++) outsc[7 + l] = scal[20 + l];
  }
}

extern "C" void kernel_launch(void* const* d_in, const int* in_sizes, int n_in,
                              void* d_out, int out_size, void* d_ws, size_t ws_size,
                              hipStream_t stream) {
  const float* x      = (const float*)d_in[0];
  const int*   ei     = (const int*)d_in[1];
  const float* enc_w  = (const float*)d_in[2];
  const float* enc_b  = (const float*)d_in[3];
  const float* conv_w = (const float*)d_in[4];
  const float* conv_b = (const float*)d_in[5];
  const int n = in_sizes[0] / 128;
  const int e = in_sizes[1] / 2;
  const int* src = ei;
  const int* dst = ei + e;
  float* OUT = (float*)d_out;
  float* outsc = OUT + (size_t)n * 64;

  char* p = (char*)d_ws;
  auto alloc = [&](size_t bytes) -> char* {
    char* r = p;
    p += (bytes + 255) & ~size_t(255);
    return r;
  };
  float*  X      = (float*)alloc((size_t)n * 64 * 4);   // h0 / h2
  float*  Yf     = (float*)alloc((size_t)n * 64 * 4);   // h1
  int*    csr    = (int*)alloc((size_t)(e + n) * 4);
  int*    degs   = (int*)alloc((size_t)n * 4);
  int*    degd   = (int*)alloc((size_t)n * 4);
  float4* cn4    = (float4*)alloc((size_t)n * 16);
  float*  degsum = (float*)alloc((size_t)n * 4);
  int*    start  = (int*)alloc((size_t)(n + 1) * 4);
  int*    cursor = (int*)alloc((size_t)n * 4);
  int*    bsum   = (int*)alloc(4096);
  float*  nsqA   = (float*)alloc((size_t)n * 4);
  float*  nsqB   = (float*)alloc((size_t)n * 4);
  float4* Pa     = (float4*)alloc((size_t)n * 16);
  float4* Pb     = (float4*)alloc((size_t)n * 16);
  float*  G      = (float*)alloc(3 * 4096 * 4);
  float*  colsum = (float*)alloc(3 * 64 * 4);
  float*  bmv    = (float*)alloc(2048 * 4);
  int*    bmi    = (int*)alloc(2048 * 4);
  float*  rowslot= (float*)alloc(3 * 64 * 4);
  float*  scal   = (float*)alloc(64 * 4);
  int*    ij     = (int*)alloc(64 * 4);

  int nb = (n + 255) / 256;
  const int NBL = 2048;

  k_init<<<nb, 256, 0, stream>>>(degs, degd, G, colsum, scal, n);
  k_deg<<<2048, 256, 0, stream>>>(src, dst, degs, degd, e);
  k_nodescal<<<nb, 256, 0, stream>>>(degs, degd, cn4, degsum, n);
  k_scan1<<<nb, 256, 0, stream>>>(degd, start, bsum, n);
  k_scan2<<<1, 512, 0, stream>>>(bsum, nb);
  k_scan3<<<nb, 256, 0, stream>>>(start, bsum, cursor, n, e + n);
  k_scatter<<<(e + n + 255) / 256, 256, 0, stream>>>(src, dst, cursor, csr, e, n);
  k_enc<<<NBL, 256, 0, stream>>>(x, enc_w, enc_b, cn4, X, nsqA, Pa, n);

  // pass 0: energy(h0) + conv0 -> h1 (Yf) + stats(h1)
  k_convpass<<<NBL, 256, 0, stream>>>(X, Pa, nsqA, degsum, cn4, start, csr,
                                      conv_w, conv_b, Yf, Pb, nsqB,
                                      scal, G, colsum, bmv, bmi, n, NBL,
                                      nullptr, nullptr, nullptr, nullptr);
  k_finalize<<<1, 64, 0, stream>>>(Yf, bmv, bmi, NBL, colsum, rowslot, ij, n);

  // pass 1: energy(h1) + conv1 -> h2 (X) + stats(h2)  ||  rank layer-1 rider
  k_convpass<<<NBL + 1, 256, 0, stream>>>(Yf, Pb, nsqB, degsum, cn4, start, csr,
                                          conv_w + 4096, conv_b + 64, X, Pa, nsqA,
                                          scal + 5, G + 4096, colsum + 64, bmv, bmi, n, NBL,
                                          G, rowslot, ij, scal + 20);
  k_finalize<<<1, 64, 0, stream>>>(X, bmv, bmi, NBL, colsum + 64, rowslot + 64, ij + 1, n);

  // pass 2: energy(h2) + conv2 -> h3 (OUT) + stats(h3)  ||  rank layer-2 rider
  k_convpass<<<NBL + 1, 256, 0, stream>>>(X, Pa, nsqA, degsum, cn4, start, csr,
                                          conv_w + 2 * 4096, conv_b + 128, OUT, Pb, nsqB,
                                          scal + 10, G + 2 * 4096, colsum + 128, bmv, bmi, n, NBL,
                                          G + 4096, rowslot + 64, ij + 1, scal + 21);
  k_finalize<<<1, 64, 0, stream>>>(OUT, bmv, bmi, NBL, colsum + 128, rowslot + 128, ij + 2, n);

  // final: rank layer 3 (block 0) || energy(h3)
  k_final<<<NBL + 1, 256, 0, stream>>>(OUT, Pb, nsqB, degsum, start, csr,
                                       scal + 15, G + 2 * 4096, rowslot + 128, ij + 2,
                                       scal + 22, n, NBL);
  k_epi<<<1, 64, 0, stream>>>(scal, outsc);
}

// Round 12
// 1416.803 us; speedup vs baseline: 1.4495x; 1.4495x over previous
//
#include <hip/hip_runtime.h>

#define WF 64

__device__ inline float wredsum(float v) {
#pragma unroll
  for (int m = 32; m; m >>= 1) v += __shfl_xor(v, m, WF);
  return v;
}
__device__ inline float4 wredsum4(float4 v) {
#pragma unroll
  for (int m = 32; m; m >>= 1) {
    v.x += __shfl_xor(v.x, m, WF);
    v.y += __shfl_xor(v.y, m, WF);
    v.z += __shfl_xor(v.z, m, WF);
    v.w += __shfl_xor(v.w, m, WF);
  }
  return v;
}
__device__ inline float wredmin(float v) {
#pragma unroll
  for (int m = 32; m; m >>= 1) v = fminf(v, __shfl_xor(v, m, WF));
  return v;
}
__device__ inline float wredmax(float v) {
#pragma unroll
  for (int m = 32; m; m >>= 1) v = fmaxf(v, __shfl_xor(v, m, WF));
  return v;
}

__device__ inline float fastrcp(float x) {
  float r;
  asm("v_rcp_f32 %0, %1" : "=v"(r) : "v"(x));
  return r;
}

__device__ inline void atomAddF(float* p, float v) { unsafeAtomicAdd(p, v); }

// ---------------- init ----------------
__global__ __launch_bounds__(256) void k_init(int* degs, int* degd, float* G,
                                              float* colsum, float* scal, int n) {
  int i = blockIdx.x * 256 + threadIdx.x;
  if (i < n) { degs[i] = 1; degd[i] = 1; }
  if (i < 3 * 4096) G[i] = 0.f;
  if (i < 3 * 64) colsum[i] = 0.f;
  if (i < 64) scal[i] = 0.f;
}

// ---------------- degree histograms ----------------
__global__ __launch_bounds__(256) void k_deg(const int* src, const int* dst,
                                             int* degs, int* degd, int e) {
  int i = blockIdx.x * 256 + threadIdx.x;
  int stride = gridDim.x * 256;
  for (; i < e; i += stride) {
    atomicAdd(&degs[src[i]], 1);
    atomicAdd(&degd[dst[i]], 1);
  }
}

// ---------------- per-node constants ----------------
__global__ __launch_bounds__(256) void k_nodescal(const int* degs, const int* degd,
                                                  float4* cn4, float* degsum, int n) {
  int i = blockIdx.x * 256 + threadIdx.x;
  if (i < n) {
    float fs = (float)degs[i], fd = (float)degd[i];
    float rs_ = rsqrtf(fs);
    float4 v;
    v.x = rsqrtf(fd);        // dis (GCN norm)
    v.y = 1.f / fs;          // 1/deg_src
    v.z = rs_;               // deg_src^-0.5
    v.w = rs_ * rs_ * rs_;   // deg_src^-1.5
    cn4[i] = v;
    degsum[i] = fs + fd;
  }
}

// ---------------- scan ----------------
__global__ __launch_bounds__(256) void k_scan1(const int* degd, int* start, int* bsum, int n) {
  __shared__ int sb[256];
  int t = threadIdx.x, i = blockIdx.x * 256 + t;
  int v = (i < n) ? degd[i] : 0;
  sb[t] = v;
  __syncthreads();
  for (int off = 1; off < 256; off <<= 1) {
    int add = (t >= off) ? sb[t - off] : 0;
    __syncthreads();
    sb[t] += add;
    __syncthreads();
  }
  if (i < n) start[i] = sb[t] - v;
  if (t == 255) bsum[blockIdx.x] = sb[255];
}

__global__ __launch_bounds__(512) void k_scan2(int* bsum, int nb) {
  __shared__ int sb[512];
  int t = threadIdx.x;
  int v = (t < nb) ? bsum[t] : 0;
  sb[t] = v;
  __syncthreads();
  for (int off = 1; off < 512; off <<= 1) {
    int add = (t >= off) ? sb[t - off] : 0;
    __syncthreads();
    sb[t] += add;
    __syncthreads();
  }
  if (t < nb) bsum[t] = sb[t] - v;
}

__global__ __launch_bounds__(256) void k_scan3(int* start, const int* bsum, int* cursor,
                                               int n, int total) {
  int i = blockIdx.x * 256 + threadIdx.x;
  if (i < n) {
    int v = start[i] + bsum[i >> 8];
    start[i] = v;
    cursor[i] = v;
  }
  if (i == 0) start[n] = total;
}

// ---------------- counting-sort edges by dst ----------------
__global__ __launch_bounds__(256) void k_scatter(const int* src, const int* dst, int* cursor,
                                                 int* csr, int e, int n) {
  int i = blockIdx.x * 256 + threadIdx.x;
  int tot = e + n;
  if (i >= tot) return;
  int s, d;
  if (i < e) { s = src[i]; d = dst[i]; } else { s = i - e; d = i - e; }
  int pos = atomicAdd(&cursor[d], 1);
  csr[pos] = s;
}

// ---------------- encoder: X = x @ enc_w + b ; nsq, P0 ----------------
__global__ __launch_bounds__(256) void k_enc(const float* __restrict__ x,
                                             const float* __restrict__ W,
                                             const float* __restrict__ b,
                                             const float4* __restrict__ cn4,
                                             float* __restrict__ X,
                                             float* __restrict__ nsq,
                                             float4* __restrict__ P, int n) {
  __shared__ float Wl[128 * 64];
  for (int idx = threadIdx.x; idx < 128 * 64; idx += 256) Wl[idx] = W[idx];
  __syncthreads();
  int w = threadIdx.x >> 6, c = threadIdx.x & 63;
  float bc = b[c];
  for (int node = blockIdx.x * 4 + w; node < n; node += gridDim.x * 4) {
    const float4* xr4 = (const float4*)(x + (size_t)node * 128);
    float acc = bc;
#pragma unroll
    for (int k4 = 0; k4 < 32; k4++) {
      float4 xv = xr4[k4];
      acc += xv.x * Wl[(k4 * 4 + 0) * 64 + c];
      acc += xv.y * Wl[(k4 * 4 + 1) * 64 + c];
      acc += xv.z * Wl[(k4 * 4 + 2) * 64 + c];
      acc += xv.w * Wl[(k4 * 4 + 3) * 64 + c];
    }
    X[(size_t)node * 64 + c] = acc;
    float r = wredsum(acc * acc);
    if (c == 0) {
      nsq[node] = r;
      float4 c4 = cn4[node];
      P[node] = make_float4(c4.x, c4.y, c4.z, r * c4.w);
    }
  }
}

// ---------------- 4-deep unrolled gather core (per 16-lane group) ----------------
template <int AGGC>
__device__ inline void gather4(const float* __restrict__ H, const float4* __restrict__ P,
                               const int* __restrict__ csr, int k0, int k1, int g, int l16,
                               float4& agg0, float4& agg1, float4& aggC,
                               float& su, float& sv) {
  int kk = k0 + g;
  int last = k1 - 1;
  int s0 = csr[min(kk, last)];
  int s1 = csr[min(kk + 4, last)];
  int s2 = csr[min(kk + 8, last)];
  int s3 = csr[min(kk + 12, last)];
  while (kk < k1) {
    int kn = kk + 16;
    float4 h0 = *(const float4*)(H + (size_t)s0 * 64 + 4 * l16);
    float4 h1 = *(const float4*)(H + (size_t)s1 * 64 + 4 * l16);
    float4 h2 = *(const float4*)(H + (size_t)s2 * 64 + 4 * l16);
    float4 h3 = *(const float4*)(H + (size_t)s3 * 64 + 4 * l16);
    float4 Q0 = P[s0], Q1 = P[s1], Q2 = P[s2], Q3 = P[s3];
    s0 = csr[min(kn, last)];
    s1 = csr[min(kn + 4, last)];
    s2 = csr[min(kn + 8, last)];
    s3 = csr[min(kn + 12, last)];
    float m1 = (kk + 4 < k1) ? 1.f : 0.f;
    float m2 = (kk + 8 < k1) ? 1.f : 0.f;
    float m3 = (kk + 12 < k1) ? 1.f : 0.f;
    agg0.x += h0.x; agg0.y += h0.y; agg0.z += h0.z; agg0.w += h0.w;
    agg1.x = fmaf(h0.x, Q0.y, agg1.x); agg1.y = fmaf(h0.y, Q0.y, agg1.y);
    agg1.z = fmaf(h0.z, Q0.y, agg1.z); agg1.w = fmaf(h0.w, Q0.y, agg1.w);
    if (AGGC) {
      aggC.x = fmaf(h0.x, Q0.x, aggC.x); aggC.y = fmaf(h0.y, Q0.x, aggC.y);
      aggC.z = fmaf(h0.z, Q0.x, aggC.z); aggC.w = fmaf(h0.w, Q0.x, aggC.w);
    }
    su += Q0.w; sv += Q0.z;
    {
      float y = Q1.y * m1;
      agg0.x = fmaf(h1.x, m1, agg0.x); agg0.y = fmaf(h1.y, m1, agg0.y);
      agg0.z = fmaf(h1.z, m1, agg0.z); agg0.w = fmaf(h1.w, m1, agg0.w);
      agg1.x = fmaf(h1.x, y, agg1.x); agg1.y = fmaf(h1.y, y, agg1.y);
      agg1.z = fmaf(h1.z, y, agg1.z); agg1.w = fmaf(h1.w, y, agg1.w);
      if (AGGC) {
        float xq = Q1.x * m1;
        aggC.x = fmaf(h1.x, xq, aggC.x); aggC.y = fmaf(h1.y, xq, aggC.y);
        aggC.z = fmaf(h1.z, xq, aggC.z); aggC.w = fmaf(h1.w, xq, aggC.w);
      }
      su = fmaf(Q1.w, m1, su); sv = fmaf(Q1.z, m1, sv);
    }
    {
      float y = Q2.y * m2;
      agg0.x = fmaf(h2.x, m2, agg0.x); agg0.y = fmaf(h2.y, m2, agg0.y);
      agg0.z = fmaf(h2.z, m2, agg0.z); agg0.w = fmaf(h2.w, m2, agg0.w);
      agg1.x = fmaf(h2.x, y, agg1.x); agg1.y = fmaf(h2.y, y, agg1.y);
      agg1.z = fmaf(h2.z, y, agg1.z); agg1.w = fmaf(h2.w, y, agg1.w);
      if (AGGC) {
        float xq = Q2.x * m2;
        aggC.x = fmaf(h2.x, xq, aggC.x); aggC.y = fmaf(h2.y, xq, aggC.y);
        aggC.z = fmaf(h2.z, xq, aggC.z); aggC.w = fmaf(h2.w, xq, aggC.w);
      }
      su = fmaf(Q2.w, m2, su); sv = fmaf(Q2.z, m2, sv);
    }
    {
      float y = Q3.y * m3;
      agg0.x = fmaf(h3.x, m3, agg0.x); agg0.y = fmaf(h3.y, m3, agg0.y);
      agg0.z = fmaf(h3.z, m3, agg0.z); agg0.w = fmaf(h3.w, m3, agg0.w);
      agg1.x = fmaf(h3.x, y, agg1.x); agg1.y = fmaf(h3.y, y, agg1.y);
      agg1.z = fmaf(h3.z, y, agg1.z); agg1.w = fmaf(h3.w, y, agg1.w);
      if (AGGC) {
        float xq = Q3.x * m3;
        aggC.x = fmaf(h3.x, xq, aggC.x); aggC.y = fmaf(h3.y, xq, aggC.y);
        aggC.z = fmaf(h3.z, xq, aggC.z); aggC.w = fmaf(h3.w, xq, aggC.w);
      }
      su = fmaf(Q3.w, m3, su); sv = fmaf(Q3.z, m3, sv);
    }
    kk = kn;
  }
}

// ---------------- fused: energy(h_l) + conv -> h_{l+1} + stats(h_{l+1}) ----------------
__global__ __launch_bounds__(256) void k_convpass(
    const float* __restrict__ H, const float4* __restrict__ P,
    const float* __restrict__ nsq, const float* __restrict__ degsum,
    const float4* __restrict__ cn4, const int* __restrict__ start,
    const int* __restrict__ csr, const float* __restrict__ W,
    const float* __restrict__ bias, float* __restrict__ T,
    float4* __restrict__ Pn, float* __restrict__ nsqN,
    float* __restrict__ scal5, float* __restrict__ G, float* __restrict__ colsum,
    float* __restrict__ bmv, int* __restrict__ bmi, int n) {
  __shared__ float Wl[4096];
  __shared__ float rowbuf[4][64];
  __shared__ float red[4][5];
  __shared__ float colred[4][64];
  __shared__ float mvs[4];
  __shared__ int mis[4];
  int t = threadIdx.x, w = t >> 6, lane = t & 63, g = lane >> 4, l16 = lane & 15;
  for (int i = t; i < 4096; i += 256) Wl[i] = W[i];
  __syncthreads();
  float a0 = 0.f, a1 = 0.f, a2 = 0.f, a3 = 0.f, a4 = 0.f;
  float Greg[16];
#pragma unroll
  for (int k = 0; k < 16; k++) Greg[k] = 0.f;
  float cacc = 0.f, best = -1.f;
  int bi = 0;
  float bc = bias[lane];
  int wid = blockIdx.x * 4 + w, nw = gridDim.x * 4;
  int iters = (n + nw - 1) / nw;
  for (int it = 0; it < iters; it++) {
    int d = wid + it * nw;
    bool valid = d < n;
    float tv = 0.f;
    if (valid) {
      int k0 = start[d], k1 = start[d + 1];
      float4 hd = *(const float4*)(H + (size_t)d * 64 + 4 * l16);
      float4 pd = P[d];
      float nqd = nsq[d];
      float dsum = degsum[d];
      float4 agg0 = {0.f, 0.f, 0.f, 0.f};
      float4 agg1 = {0.f, 0.f, 0.f, 0.f};
      float4 aggC = {0.f, 0.f, 0.f, 0.f};
      float su = 0.f, sv = 0.f;
      gather4<1>(H, P, csr, k0, k1, g, l16, agg0, agg1, aggC, su, sv);
      float td0 = agg0.x * hd.x + agg0.y * hd.y + agg0.z * hd.z + agg0.w * hd.w;
      float td1 = agg1.x * hd.x + agg1.y * hd.y + agg1.z * hd.z + agg1.w * hd.w;
      float4 r4 = wredsum4(make_float4(td0, td1, su, sv));
      float dot1 = r4.x, dot2 = r4.y;
      su = r4.z * 0.0625f;
      sv = r4.w * 0.0625f;
      a0 += dsum * nqd;
      a1 += dot1;
      a2 += pd.z * su + pd.w * sv;
      a3 += pd.y * dot2;
      a4 += nqd;
      aggC.x += __shfl_xor(aggC.x, 16); aggC.y += __shfl_xor(aggC.y, 16);
      aggC.z += __shfl_xor(aggC.z, 16); aggC.w += __shfl_xor(aggC.w, 16);
      aggC.x += __shfl_xor(aggC.x, 32); aggC.y += __shfl_xor(aggC.y, 32);
      aggC.z += __shfl_xor(aggC.z, 32); aggC.w += __shfl_xor(aggC.w, 32);
      float mv = 0.f;
#pragma unroll
      for (int kq = 0; kq < 16; kq++) {
        float ax = __shfl(aggC.x, kq, 16);
        float ay = __shfl(aggC.y, kq, 16);
        float az = __shfl(aggC.z, kq, 16);
        float aw = __shfl(aggC.w, kq, 16);
        mv += ax * Wl[(4 * kq + 0) * 64 + lane];
        mv += ay * Wl[(4 * kq + 1) * 64 + lane];
        mv += az * Wl[(4 * kq + 2) * 64 + lane];
        mv += aw * Wl[(4 * kq + 3) * 64 + lane];
      }
      tv = fmaxf(fmaf(pd.x, mv, bc), 0.f);
      T[(size_t)d * 64 + lane] = tv;
      float r = wredsum(tv * tv);
      float atv = fabsf(tv);
      cacc += atv;
      float rsum = wredsum(atv);
      if (rsum > best) { best = rsum; bi = d; }
      if (lane == 0) {
        nsqN[d] = r;
        float4 c4 = cn4[d];
        Pn[d] = make_float4(c4.x, c4.y, c4.z, r * c4.w);
      }
    }
    rowbuf[w][lane] = tv;
    __syncthreads();
#pragma unroll
    for (int rr = 0; rr < 4; rr++) {
      float hj = rowbuf[rr][lane];
#pragma unroll
      for (int k = 0; k < 16; k++) Greg[k] = fmaf(rowbuf[rr][w + 4 * k], hj, Greg[k]);
    }
    __syncthreads();
  }
#pragma unroll
  for (int k = 0; k < 16; k++) atomAddF(&G[(w + 4 * k) * 64 + lane], Greg[k]);
  colred[w][lane] = cacc;
  if (lane == 0) {
    red[w][0] = a0; red[w][1] = a1; red[w][2] = a2; red[w][3] = a3; red[w][4] = a4;
    mvs[w] = best; mis[w] = bi;
  }
  __syncthreads();
  if (t < 64) {
    float cs = colred[0][t] + colred[1][t] + colred[2][t] + colred[3][t];
    atomAddF(&colsum[t], cs);
  }
  if (t == 0) {
#pragma unroll
    for (int j = 0; j < 5; j++)
      atomAddF(&scal5[j], red[0][j] + red[1][j] + red[2][j] + red[3][j]);
    float bv = mvs[0]; int bix = mis[0];
    for (int q = 1; q < 4; q++)
      if (mvs[q] > bv || (mvs[q] == bv && mis[q] < bix)) { bv = mvs[q]; bix = mis[q]; }
    bmv[blockIdx.x] = bv;
    bmi[blockIdx.x] = bix;
  }
}

// ---------------- finalize argmaxes (one wave) ----------------
__global__ __launch_bounds__(64) void k_finalize(const float* T, const float* bmv,
                                                 const int* bmi, int nblocks,
                                                 const float* colsum, float* rowslot,
                                                 int* jstar, int n) {
  int t = threadIdx.x;
  float bv = -1.f;
  int bix = 0x7fffffff;
  for (int b = t; b < nblocks; b += 64) {
    float v = bmv[b]; int ix = bmi[b];
    if (v > bv || (v == bv && ix < bix)) { bv = v; bix = ix; }
  }
#pragma unroll
  for (int m = 32; m; m >>= 1) {
    float ov = __shfl_xor(bv, m); int oi = __shfl_xor(bix, m);
    if (ov > bv || (ov == bv && oi < bix)) { bv = ov; bix = oi; }
  }
  float cv = colsum[t];
  int cj = t;
#pragma unroll
  for (int m = 32; m; m >>= 1) {
    float ov = __shfl_xor(cv, m); int oj = __shfl_xor(cj, m);
    if (ov > cv || (ov == cv && oj < cj)) { cv = ov; cj = oj; }
  }
  if (t == 0) jstar[0] = cj;
  rowslot[t] = T[(size_t)bix * 64 + t];
}

// ---------------- Householder tridiag (trailing-only) + Sturm bisection --------------
__device__ float tridiag_sumsqrt(float (*A)[65], float* vbuf, float* wbuf,
                                 float (*wpart)[64], float2* de, float* esh, int t) {
  bool w0 = (t < 64);
  int lane = t & 63, w4 = t >> 6;
  for (int k = 0; k < 62; k++) {
    float beta = 0.f;
    if (w0) {
      float acol = A[t][k];
      float xs = (t >= k + 2) ? acol : 0.f;
      float sigma = wredsum(xs * xs);
      float x1 = __shfl(acol, k + 1, WF);
      float alpha = -copysignf(sqrtf(fmaf(x1, x1, sigma)), x1);
      float v1 = x1 - alpha;
      float vv = fmaf(v1, v1, sigma);
      beta = (vv > 1e-37f) ? 2.f / vv : 0.f;
      vbuf[t] = (t == k + 1) ? v1 : xs;   // zero for t<=k
      if (t == 0) esh[k] = alpha;
    }
    __syncthreads();
    {
      float s0 = 0.f, s1 = 0.f, s2 = 0.f, s3 = 0.f;
#pragma unroll
      for (int i2 = 0; i2 < 4; i2++) {
        int j = w4 + 16 * i2;
        if (j > k)      s0 = fmaf(A[lane][j], vbuf[j], s0);
        if (j + 4 > k)  s1 = fmaf(A[lane][j + 4], vbuf[j + 4], s1);
        if (j + 8 > k)  s2 = fmaf(A[lane][j + 8], vbuf[j + 8], s2);
        if (j + 12 > k) s3 = fmaf(A[lane][j + 12], vbuf[j + 12], s3);
      }
      wpart[w4][lane] = (s0 + s1) + (s2 + s3);
    }
    __syncthreads();
    if (w0) {
      float p = beta * (wpart[0][t] + wpart[1][t] + wpart[2][t] + wpart[3][t]);
      float dot = wredsum(vbuf[t] * p);
      float K = 0.5f * beta * dot;
      wbuf[t] = fmaf(-K, vbuf[t], p);
    }
    __syncthreads();
    {
      float vj = vbuf[lane], wj = wbuf[lane];
#pragma unroll
      for (int i2 = 0; i2 < 16; i2++) {
        int i = w4 + 4 * i2;
        if (i > k) A[i][lane] -= vbuf[i] * wj + wbuf[i] * vj;
      }
    }
    __syncthreads();
  }
  if (t == 0) { esh[62] = A[63][62]; esh[63] = 0.f; }
  __syncthreads();
  float gmin = 0.f, gmax = 0.f;
  if (w0) {
    float dt = A[t][t];
    float ep = (t >= 1) ? esh[t - 1] : 0.f;
    float en = (t <= 62) ? esh[t] : 0.f;
    de[t] = make_float2(dt, ep * ep);
    float rad = fabsf(ep) + fabsf(en);
    gmin = wredmin(dt - rad);
    gmax = wredmax(dt + rad);
  }
  __syncthreads();
  float lam = 0.f;
  if (w0) {
    float range = gmax - gmin;
    float lo = gmin - 1e-3f * range - 1e-30f;
    float hi = gmax + 1e-3f * range + 1e-30f;
    for (int it = 0; it < 30; it++) {
      float mid = 0.5f * (lo + hi);
      float q = de[0].x - mid;
      int cnt = (q < 0.f) ? 1 : 0;
      for (int i = 1; i < 64; i++) {
        float2 dc = de[i];
        float qq = (dc.x - mid) - dc.y * fastrcp(q);
        q = (fabsf(qq) < 1e-30f) ? -1e-30f : qq;
        cnt += (q < 0.f) ? 1 : 0;
      }
      if (cnt > t) hi = mid; else lo = mid;
    }
    lam = 0.5f * (lo + hi);
  }
  float svv = w0 ? sqrtf(fmaxf(lam, 0.f)) : 0.f;
  return wredsum(svv);
}

// ---------------- final: 3 rank blocks + energy(h3) blocks ----------------
__global__ __launch_bounds__(256) void k_final(
    const float* __restrict__ H, const float4* __restrict__ P,
    const float* __restrict__ nsq, const float* __restrict__ degsum,
    const int* __restrict__ start, const int* __restrict__ csr,
    float* __restrict__ scal5, const float* __restrict__ Gbase,
    const float* __restrict__ rowslot, const int* __restrict__ jstar,
    float* __restrict__ rankOut, int n, int nbE) {
  __shared__ float A[64][65];
  __shared__ float vbuf[64], wbuf[64], esh[64];
  __shared__ float wpart[4][64];
  __shared__ float2 de[64];
  __shared__ float u[64], m0[64];
  __shared__ float shn;
  __shared__ float red[4][5];
  int t = threadIdx.x, w = t >> 6, lane = t & 63, g = lane >> 4, l16 = lane & 15;
  if (blockIdx.x < 3) {
    int l = blockIdx.x;
    const float* Gl = Gbase + l * 4096;
    for (int idx = t; idx < 4096; idx += 256) A[idx >> 6][idx & 63] = Gl[idx];
    __syncthreads();
    float nuc1 = tridiag_sumsqrt(A, vbuf, wbuf, wpart, de, esh, t);
    if (t == 0) shn = nuc1;
    __syncthreads();
    float s = 1.f / shn;
    int js = jstar[l];
    if (t < 64) {
      float rv = rowslot[l * 64 + t];
      float rn2 = wredsum(rv * rv);
      float sign = (rowslot[l * 64 + js] < 0.f) ? -1.f : 1.f;
      m0[t] = sign * rv * rsqrtf(rn2);
      u[t] = s * Gl[t * 64 + js] * rsqrtf(Gl[js * 64 + js]);
    }
    __syncthreads();
    float s2 = s * s;
    for (int idx = t; idx < 4096; idx += 256) {
      int i = idx >> 6, j = idx & 63;
      A[i][j] = s2 * Gl[idx] - u[i] * m0[j] - m0[i] * u[j] + m0[i] * m0[j];
    }
    __syncthreads();
    float nuc2 = tridiag_sumsqrt(A, vbuf, wbuf, wpart, de, esh, t);
    if (t == 0) rankOut[l] = nuc2;
    return;
  }
  float a0 = 0.f, a1 = 0.f, a2 = 0.f, a3 = 0.f, a4 = 0.f;
  int wid = (blockIdx.x - 3) * 4 + w, nw = nbE * 4;
  for (int d = wid; d < n; d += nw) {
    int k0 = start[d], k1 = start[d + 1];
    float4 hd = *(const float4*)(H + (size_t)d * 64 + 4 * l16);
    float4 pd = P[d];
    float nqd = nsq[d];
    float dsum = degsum[d];
    float4 agg0 = {0.f, 0.f, 0.f, 0.f};
    float4 agg1 = {0.f, 0.f, 0.f, 0.f};
    float4 aggC = {0.f, 0.f, 0.f, 0.f};
    float su = 0.f, sv = 0.f;
    gather4<0>(H, P, csr, k0, k1, g, l16, agg0, agg1, aggC, su, sv);
    float td0 = agg0.x * hd.x + agg0.y * hd.y + agg0.z * hd.z + agg0.w * hd.w;
    float td1 = agg1.x * hd.x + agg1.y * hd.y + agg1.z * hd.z + agg1.w * hd.w;
    float4 r4 = wredsum4(make_float4(td0, td1, su, sv));
    a0 += dsum * nqd;
    a1 += r4.x;
    a2 += pd.z * (r4.z * 0.0625f) + pd.w * (r4.w * 0.0625f);
    a3 += pd.y * r4.y;
    a4 += nqd;
  }
  if (lane == 0) {
    red[w][0] = a0; red[w][1] = a1; red[w][2] = a2; red[w][3] = a3; red[w][4] = a4;
  }
  __syncthreads();
  if (t == 0) {
#pragma unroll
    for (int j = 0; j < 5; j++)
      atomAddF(&scal5[j], red[0][j] + red[1][j] + red[2][j] + red[3][j]);
  }
}

// ---------------- epilogue ----------------
__global__ __launch_bounds__(64) void k_epi(const float* scal, float* outsc) {
  if (threadIdx.x == 0) {
    for (int st = 0; st < 4; st++) {
      const float* a = scal + 5 * st;
      float inv = 1.f / a[4];
      float rw = 0.5f * (a[0] - 2.f * a[1]) * inv;
      float sym = 0.5f * (a[2] - 2.f * a[3]) * inv;
      if (st == 0) outsc[0] = sym;
      else { outsc[st] = rw; outsc[3 + st] = sym; }
    }
    for (int l = 0; l < 3; l++) outsc[7 + l] = scal[20 + l];
  }
}

extern "C" void kernel_launch(void* const* d_in, const int* in_sizes, int n_in,
                              void* d_out, int out_size, void* d_ws, size_t ws_size,
                              hipStream_t stream) {
  const float* x      = (const float*)d_in[0];
  const int*   ei     = (const int*)d_in[1];
  const float* enc_w  = (const float*)d_in[2];
  const float* enc_b  = (const float*)d_in[3];
  const float* conv_w = (const float*)d_in[4];
  const float* conv_b = (const float*)d_in[5];
  const int n = in_sizes[0] / 128;
  const int e = in_sizes[1] / 2;
  const int* src = ei;
  const int* dst = ei + e;
  float* OUT = (float*)d_out;
  float* outsc = OUT + (size_t)n * 64;

  char* p = (char*)d_ws;
  auto alloc = [&](size_t bytes) -> char* {
    char* r = p;
    p += (bytes + 255) & ~size_t(255);
    return r;
  };
  float*  X      = (float*)alloc((size_t)n * 64 * 4);   // h0 / h2
  float*  Yf     = (float*)alloc((size_t)n * 64 * 4);   // h1
  int*    csr    = (int*)alloc((size_t)(e + n) * 4);
  int*    degs   = (int*)alloc((size_t)n * 4);
  int*    degd   = (int*)alloc((size_t)n * 4);
  float4* cn4    = (float4*)alloc((size_t)n * 16);
  float*  degsum = (float*)alloc((size_t)n * 4);
  int*    start  = (int*)alloc((size_t)(n + 1) * 4);
  int*    cursor = (int*)alloc((size_t)n * 4);
  int*    bsum   = (int*)alloc(4096);
  float*  nsqA   = (float*)alloc((size_t)n * 4);
  float*  nsqB   = (float*)alloc((size_t)n * 4);
  float4* Pa     = (float4*)alloc((size_t)n * 16);
  float4* Pb     = (float4*)alloc((size_t)n * 16);
  float*  G      = (float*)alloc(3 * 4096 * 4);
  float*  colsum = (float*)alloc(3 * 64 * 4);
  float*  bmv    = (float*)alloc(2048 * 4);
  int*    bmi    = (int*)alloc(2048 * 4);
  float*  rowslot= (float*)alloc(3 * 64 * 4);
  float*  scal   = (float*)alloc(64 * 4);
  int*    ij     = (int*)alloc(64 * 4);

  int nb = (n + 255) / 256;
  const int NBL = 2048;

  k_init<<<nb, 256, 0, stream>>>(degs, degd, G, colsum, scal, n);
  k_deg<<<2048, 256, 0, stream>>>(src, dst, degs, degd, e);
  k_nodescal<<<nb, 256, 0, stream>>>(degs, degd, cn4, degsum, n);
  k_scan1<<<nb, 256, 0, stream>>>(degd, start, bsum, n);
  k_scan2<<<1, 512, 0, stream>>>(bsum, nb);
  k_scan3<<<nb, 256, 0, stream>>>(start, bsum, cursor, n, e + n);
  k_scatter<<<(e + n + 255) / 256, 256, 0, stream>>>(src, dst, cursor, csr, e, n);
  k_enc<<<NBL, 256, 0, stream>>>(x, enc_w, enc_b, cn4, X, nsqA, Pa, n);

  // pass 0: energy(h0) + conv0 -> h1 (Yf) + stats(h1)
  k_convpass<<<NBL, 256, 0, stream>>>(X, Pa, nsqA, degsum, cn4, start, csr,
                                      conv_w, conv_b, Yf, Pb, nsqB,
                                      scal, G, colsum, bmv, bmi, n);
  k_finalize<<<1, 64, 0, stream>>>(Yf, bmv, bmi, NBL, colsum, rowslot, ij, n);

  // pass 1: energy(h1) + conv1 -> h2 (X) + stats(h2)
  k_convpass<<<NBL, 256, 0, stream>>>(Yf, Pb, nsqB, degsum, cn4, start, csr,
                                      conv_w + 4096, conv_b + 64, X, Pa, nsqA,
                                      scal + 5, G + 4096, colsum + 64, bmv, bmi, n);
  k_finalize<<<1, 64, 0, stream>>>(X, bmv, bmi, NBL, colsum + 64, rowslot + 64, ij + 1, n);

  // pass 2: energy(h2) + conv2 -> h3 (OUT) + stats(h3)
  k_convpass<<<NBL, 256, 0, stream>>>(X, Pa, nsqA, degsum, cn4, start, csr,
                                      conv_w + 2 * 4096, conv_b + 128, OUT, Pb, nsqB,
                                      scal + 10, G + 2 * 4096, colsum + 128, bmv, bmi, n);
  k_finalize<<<1, 64, 0, stream>>>(OUT, bmv, bmi, NBL, colsum + 128, rowslot + 128, ij + 2, n);

  // final: rank layers 1-3 (blocks 0..2) || energy(h3)
  k_final<<<NBL + 3, 256, 0, stream>>>(OUT, Pb, nsqB, degsum, start, csr,
                                       scal + 15, G, rowslot, ij, scal + 20, n, NBL);
  k_epi<<<1, 64, 0, stream>>>(scal, outsc);
}